// Round 2
// baseline (759.601 us; speedup 1.0000x reference)
//
#include <hip/hip_runtime.h>
#include <hip/hip_bf16.h>
#include <math.h>

#define B 64
#define N 512
#define C 1024
#define K_NEIGH 32
#define DELTA 0.0625f   // band half-width; must exceed 2*eps of split-bf16 GEMM (~9e-3 worst)

typedef __attribute__((ext_vector_type(8))) short bf16x8;
typedef __attribute__((ext_vector_type(4))) float f32x4;

union Pack { unsigned short u[8]; bf16x8 v; };

// fp32 -> (hi bf16, lo bf16) split, both RNE. hi exact in fp32 for residual.
__device__ inline void split_bf16(float f, unsigned short& h, unsigned short& l) {
    unsigned u = __builtin_bit_cast(unsigned, f);
    unsigned r = (u + 0x7FFFu + ((u >> 16) & 1u)) & 0xFFFF0000u;
    h = (unsigned short)(r >> 16);
    float hf = __builtin_bit_cast(float, r);
    float lo = f - hf;                       // exact
    unsigned u2 = __builtin_bit_cast(unsigned, lo);
    l = (unsigned short)((u2 + 0x7FFFu + ((u2 >> 16) & 1u)) >> 16);
}

__device__ inline void cvt8(float4 f0, float4 f1, Pack& ph, Pack& pl) {
    split_bf16(f0.x, ph.u[0], pl.u[0]); split_bf16(f0.y, ph.u[1], pl.u[1]);
    split_bf16(f0.z, ph.u[2], pl.u[2]); split_bf16(f0.w, ph.u[3], pl.u[3]);
    split_bf16(f1.x, ph.u[4], pl.u[4]); split_bf16(f1.y, ph.u[5], pl.u[5]);
    split_bf16(f1.z, ph.u[6], pl.u[6]); split_bf16(f1.w, ph.u[7], pl.u[7]);
}

// ---------------------------------------------------------------------------
// Kernel 1: S'[b] = hi*hi^T + hi*lo^T + lo*hi^T via bf16 MFMA.
// 128x128 tile per block (256 thr = 4 waves, each 64x64 = 4x4 of 16x16x32).
// LDS granule layout: granule (s,row) = 8 bf16 of k=s*8.. at offset (s*128+row)*16B
//   -> frag read for lane l: granule (s=l>>4, row=base+(l&15)) = contiguous 256B
//      per 16-lane group (conflict-free b128).
// A-frag layout (guide-verified): A[m=lane&15][k=(lane>>4)*8+j]
// C/D layout  (m89/m91 verified): col=lane&15, row=(lane>>4)*4+reg
// ---------------------------------------------------------------------------
__global__ __launch_bounds__(256, 3) void gemm_split(const float* __restrict__ x,
                                                     float* __restrict__ S) {
    __shared__ bf16x8 Ah[512], Al[512], Bh[512], Bl[512];   // 4 x 8KB

    const int b = blockIdx.x;
    int p = blockIdx.y;            // 0..9 -> (ti,tj), tj>=ti over 4x4 strips of 128
    int ti = 0;
    while (p >= (4 - ti)) { p -= (4 - ti); ti++; }
    const int tj = ti + p;
    const int row0A = ti * 128;
    const int row0B = tj * 128;
    const float* xb = x + (size_t)b * N * C;

    const int t    = threadIdx.x;
    const int w    = t >> 6;
    const int lane = t & 63;
    const int quad = lane >> 4;
    const int lid  = lane & 15;
    const int wr   = (w >> 1) * 64;
    const int wc   = (w & 1) * 64;

    // staging assignment: thread t -> row (t>>1), k-half (t&1)*16 (2 granules)
    const int srow = t >> 1;
    const int sg   = (t & 1) * 2;

    f32x4 acc[4][4];
#pragma unroll
    for (int r = 0; r < 4; r++)
#pragma unroll
        for (int c = 0; c < 4; c++)
#pragma unroll
            for (int e = 0; e < 4; e++) acc[r][c][e] = 0.f;

    for (int kt = 0; kt < C; kt += 32) {
        {   // stage A strip row
            const float* pa = xb + (size_t)(row0A + srow) * C + kt + sg * 8;
            float4 f0 = ((const float4*)pa)[0];
            float4 f1 = ((const float4*)pa)[1];
            float4 f2 = ((const float4*)pa)[2];
            float4 f3 = ((const float4*)pa)[3];
            Pack h0, l0, h1, l1;
            cvt8(f0, f1, h0, l0);
            cvt8(f2, f3, h1, l1);
            Ah[sg * 128 + srow]       = h0.v;  Al[sg * 128 + srow]       = l0.v;
            Ah[(sg + 1) * 128 + srow] = h1.v;  Al[(sg + 1) * 128 + srow] = l1.v;
        }
        {   // stage B strip row
            const float* pb = xb + (size_t)(row0B + srow) * C + kt + sg * 8;
            float4 f0 = ((const float4*)pb)[0];
            float4 f1 = ((const float4*)pb)[1];
            float4 f2 = ((const float4*)pb)[2];
            float4 f3 = ((const float4*)pb)[3];
            Pack h0, l0, h1, l1;
            cvt8(f0, f1, h0, l0);
            cvt8(f2, f3, h1, l1);
            Bh[sg * 128 + srow]       = h0.v;  Bl[sg * 128 + srow]       = l0.v;
            Bh[(sg + 1) * 128 + srow] = h1.v;  Bl[(sg + 1) * 128 + srow] = l1.v;
        }
        __syncthreads();

        bf16x8 vbh[4], vbl[4];
#pragma unroll
        for (int c = 0; c < 4; c++) {
            vbh[c] = Bh[quad * 128 + wc + c * 16 + lid];
            vbl[c] = Bl[quad * 128 + wc + c * 16 + lid];
        }
#pragma unroll
        for (int r = 0; r < 4; r++) {
            bf16x8 vah = Ah[quad * 128 + wr + r * 16 + lid];
            bf16x8 val = Al[quad * 128 + wr + r * 16 + lid];
#pragma unroll
            for (int c = 0; c < 4; c++) {
                acc[r][c] = __builtin_amdgcn_mfma_f32_16x16x32_bf16(vah, vbh[c], acc[r][c], 0, 0, 0);
                acc[r][c] = __builtin_amdgcn_mfma_f32_16x16x32_bf16(vah, vbl[c], acc[r][c], 0, 0, 0);
                acc[r][c] = __builtin_amdgcn_mfma_f32_16x16x32_bf16(val, vbh[c], acc[r][c], 0, 0, 0);
            }
        }
        __syncthreads();
    }

    float* Sb = S + (size_t)b * N * N;
#pragma unroll
    for (int r = 0; r < 4; r++) {
#pragma unroll
        for (int c = 0; c < 4; c++) {
#pragma unroll
            for (int e = 0; e < 4; e++) {
                const int grow = row0A + wr + r * 16 + quad * 4 + e;
                const int gcol = row0B + wc + c * 16 + lid;
                const float vv = acc[r][c][e];
                Sb[(size_t)grow * N + gcol] = vv;
                if (ti != tj) Sb[(size_t)gcol * N + grow] = vv;
            }
        }
    }
}

// ---------------------------------------------------------------------------
// Kernel 2: per row: approx 32nd-largest T' of S'; classify with margin DELTA;
// recompute band entries EXACTLY (ascending-k fp32 fmaf = reference order);
// derive exact threshold T, adjacency bitmask (512 bits), degree, deg^-0.5.
// One wave per row, 4 rows per block.
// ---------------------------------------------------------------------------
__global__ __launch_bounds__(256) void thresh_mask(const float* __restrict__ S,
                                                   const float* __restrict__ x,
                                                   unsigned long long* __restrict__ masks,
                                                   float* __restrict__ dinv) {
    const int row  = blockIdx.x * 4 + (threadIdx.x >> 6);
    const int lane = threadIdx.x & 63;
    const float* Srow = S + (size_t)row * N;

    float v[8], v0[8];
#pragma unroll
    for (int k = 0; k < 8; k++) { v[k] = Srow[lane + 64 * k]; v0[k] = v[k]; }

    float lmax = -INFINITY;
#pragma unroll
    for (int k = 0; k < 8; k++) lmax = fmaxf(lmax, v[k]);

    // iterative extraction of approx 32nd-largest T'
    float Tp = -INFINITY;
    for (int it = 0; it < K_NEIGH; it++) {
        float m = lmax;
#pragma unroll
        for (int off = 32; off > 0; off >>= 1) m = fmaxf(m, __shfl_xor(m, off));
        Tp = m;
        unsigned long long ball = __ballot(lmax == m);
        int first = __ffsll(ball) - 1;
        if (lane == first) {
            bool removed = false;
#pragma unroll
            for (int k = 0; k < 8; k++)
                if (!removed && v[k] == m) { v[k] = -INFINITY; removed = true; }
            lmax = -INFINITY;
#pragma unroll
            for (int k = 0; k < 8; k++) lmax = fmaxf(lmax, v[k]);
        }
    }

    const float hiB = Tp + DELTA, loB = Tp - DELTA;

    // |A| = #{S' > T'+delta}  (certainly-in set; <= 31 by construction)
    int cA = 0;
#pragma unroll
    for (int k = 0; k < 8; k++) cA += (v0[k] > hiB) ? 1 : 0;
#pragma unroll
    for (int off = 32; off > 0; off >>= 1) cA += __shfl_xor(cA, off);
    const int m_need = K_NEIGH - cA;   // >= 1

    // collect band candidates: one per lane
    int cnt = 0, myj = -1;
#pragma unroll
    for (int kq = 0; kq < 8; kq++) {
        unsigned long long bm = __ballot(v0[kq] >= loB && v0[kq] <= hiB);
        while (bm) {
            int bl = __ffsll(bm) - 1;
            bm &= bm - 1;
            if (cnt == lane) myj = bl + 64 * kq;
            cnt++;
        }
    }
    const int nc = cnt < 64 ? cnt : 64;

    // exact dot (ascending k, scalar fmaf chain = reference accumulation order)
    const int bb_ = row >> 9, ii = row & (N - 1);
    float ex = -INFINITY;
    if (lane < nc) {
        const float* xi = x + ((size_t)bb_ * N + ii) * C;
        const float* xj = x + ((size_t)bb_ * N + myj) * C;
        float a = 0.f;
        for (int k = 0; k < C; k += 4) {
            float4 pa = *(const float4*)(xi + k);
            float4 pb = *(const float4*)(xj + k);
            a = fmaf(pa.x, pb.x, a);
            a = fmaf(pa.y, pb.y, a);
            a = fmaf(pa.z, pb.z, a);
            a = fmaf(pa.w, pb.w, a);
        }
        ex = a;
    }

    // exact threshold T = m_need-th largest of band exact values
    float val = ex, T = -INFINITY;
    for (int it = 0; it < m_need; it++) {
        float M = val;
#pragma unroll
        for (int off = 32; off > 0; off >>= 1) M = fmaxf(M, __shfl_xor(M, off));
        T = M;
        unsigned long long ball = __ballot(val == M);
        int first = __ffsll(ball) - 1;
        if (lane == first) val = -INFINITY;
    }

    const int dec = (lane < nc && ex >= T) ? 1 : 0;

    // adjacency bits: A -> 1, band -> exact decision, else 0
    int bits[8];
#pragma unroll
    for (int kq = 0; kq < 8; kq++) bits[kq] = (v0[kq] > hiB) ? 1 : 0;
    for (int c2 = 0; c2 < nc; c2++) {
        int j = __shfl(myj, c2);
        int d = __shfl(dec, c2);
        if ((j & 63) == lane) bits[j >> 6] = d;
    }

    unsigned long long msk[8];
    int deg = 0;
#pragma unroll
    for (int kq = 0; kq < 8; kq++) {
        msk[kq] = __ballot(bits[kq] != 0);
        deg += __popcll(msk[kq]);
    }
    if (lane == 0) {
#pragma unroll
        for (int kq = 0; kq < 8; kq++) masks[(size_t)row * 8 + kq] = msk[kq];
        dinv[row] = rsqrtf((float)deg);
    }
}

// ---------------------------------------------------------------------------
// Kernel 3: out[b,i,j] = maskbit ? dinv[b,i]*dinv[b,j] : 0  (writes over S')
// ---------------------------------------------------------------------------
__global__ __launch_bounds__(256) void scale_adj(float* __restrict__ Sout,
                                                 const unsigned long long* __restrict__ masks,
                                                 const float* __restrict__ dinv) {
    const int idx = blockIdx.x * 256 + threadIdx.x;   // float4 index
    const int jq = idx & 127;            // j4 group, j0 = jq*4
    const int i  = (idx >> 7) & (N - 1);
    const int b  = idx >> 16;
    const int row = (b << 9) | i;
    const int j0 = jq * 4;

    const unsigned long long mk = masks[(size_t)row * 8 + (j0 >> 6)];
    const float di = dinv[row];
    float4 dj = ((const float4*)dinv)[(b << 7) | jq];

    float4 o;
    o.x = ((mk >> ((j0 + 0) & 63)) & 1ull) ? di * dj.x : 0.f;
    o.y = ((mk >> ((j0 + 1) & 63)) & 1ull) ? di * dj.y : 0.f;
    o.z = ((mk >> ((j0 + 2) & 63)) & 1ull) ? di * dj.z : 0.f;
    o.w = ((mk >> ((j0 + 3) & 63)) & 1ull) ? di * dj.w : 0.f;
    ((float4*)Sout)[idx] = o;
}

// ---------------------------------------------------------------------------
extern "C" void kernel_launch(void* const* d_in, const int* in_sizes, int n_in,
                              void* d_out, int out_size, void* d_ws, size_t ws_size,
                              hipStream_t stream) {
    const float* x = (const float*)d_in[0];
    float* out = (float*)d_out;                      // stages S', then final output
    unsigned long long* masks = (unsigned long long*)d_ws;     // B*N*8 u64 = 2MB
    float* dinv = (float*)(masks + (size_t)B * N * 8);         // B*N floats

    dim3 g1(B, 10);                                  // 10 = upper-tri pairs of 4 strips
    gemm_split<<<g1, 256, 0, stream>>>(x, out);
    thresh_mask<<<B * N / 4, 256, 0, stream>>>(out, x, masks, dinv);
    const int total4 = B * N * N / 4;
    scale_adj<<<total4 / 256, 256, 0, stream>>>(out, masks, dinv);
}

// Round 3
// 329.112 us; speedup vs baseline: 2.3080x; 2.3080x over previous
//
#include <hip/hip_runtime.h>
#include <hip/hip_bf16.h>
#include <math.h>

#define B 64
#define N 512
#define C 1024
#define K_NEIGH 32
// band half-width: must satisfy DELTA - bisect_window/2 - E > E, where
// E ~ 0.15 (9-sigma bound on fp16-hi GEMM error) and window = 2800/2^14 = 0.17.
// 0.625 - 0.085 - 0.15 = 0.39 > 0.15  -> non-band elements strictly separated
// from the true 32nd-rank cut; band candidates are exactly rechecked in fp32.
#define DELTA 0.625f
#define BISECT_ITERS 14

typedef __attribute__((ext_vector_type(8))) _Float16 half8;
typedef __attribute__((ext_vector_type(4))) float f32x4;

// ---------------------------------------------------------------------------
// Kernel 1: S'[b] = fp16(x[b]) * fp16(x[b])^T via f16 MFMA (hi-only).
// 128x128 tile per block (256 thr = 4 waves, each 64x64 = 4x4 of 16x16x32).
// LDS granule layout: granule (s,row) = 8 fp16 of k=s*8.. at index s*128+row
//   -> frag read lane l: granule (s=l>>4, row=base+(l&15)) contiguous b128.
// A-frag: A[m=lane&15][k=(lane>>4)*8+j]; C/D: col=lane&15,row=(lane>>4)*4+reg
// ---------------------------------------------------------------------------
__global__ __launch_bounds__(256) void gemm_f16(const float* __restrict__ x,
                                                float* __restrict__ S) {
    __shared__ half8 Ah[512], Bh[512];   // 2 x 8KB

    const int b = blockIdx.x;
    int p = blockIdx.y;            // 0..9 -> (ti,tj), tj>=ti over 4 strips of 128
    int ti = 0;
    while (p >= (4 - ti)) { p -= (4 - ti); ti++; }
    const int tj = ti + p;
    const int row0A = ti * 128;
    const int row0B = tj * 128;
    const float* xb = x + (size_t)b * N * C;

    const int t    = threadIdx.x;
    const int w    = t >> 6;
    const int lane = t & 63;
    const int quad = lane >> 4;
    const int lid  = lane & 15;
    const int wr   = (w >> 1) * 64;
    const int wc   = (w & 1) * 64;

    // staging: thread t -> row (t>>1), k-half (t&1)*16 (granules sg, sg+1)
    const int srow = t >> 1;
    const int sg   = (t & 1) * 2;

    f32x4 acc[4][4];
#pragma unroll
    for (int r = 0; r < 4; r++)
#pragma unroll
        for (int c = 0; c < 4; c++)
#pragma unroll
            for (int e = 0; e < 4; e++) acc[r][c][e] = 0.f;

    for (int kt = 0; kt < C; kt += 32) {
        {
            const float* pa = xb + (size_t)(row0A + srow) * C + kt + sg * 8;
            float4 f0 = ((const float4*)pa)[0];
            float4 f1 = ((const float4*)pa)[1];
            float4 f2 = ((const float4*)pa)[2];
            float4 f3 = ((const float4*)pa)[3];
            half8 g0, g1;
            g0[0] = (_Float16)f0.x; g0[1] = (_Float16)f0.y; g0[2] = (_Float16)f0.z; g0[3] = (_Float16)f0.w;
            g0[4] = (_Float16)f1.x; g0[5] = (_Float16)f1.y; g0[6] = (_Float16)f1.z; g0[7] = (_Float16)f1.w;
            g1[0] = (_Float16)f2.x; g1[1] = (_Float16)f2.y; g1[2] = (_Float16)f2.z; g1[3] = (_Float16)f2.w;
            g1[4] = (_Float16)f3.x; g1[5] = (_Float16)f3.y; g1[6] = (_Float16)f3.z; g1[7] = (_Float16)f3.w;
            Ah[sg * 128 + srow]       = g0;
            Ah[(sg + 1) * 128 + srow] = g1;
        }
        {
            const float* pb = xb + (size_t)(row0B + srow) * C + kt + sg * 8;
            float4 f0 = ((const float4*)pb)[0];
            float4 f1 = ((const float4*)pb)[1];
            float4 f2 = ((const float4*)pb)[2];
            float4 f3 = ((const float4*)pb)[3];
            half8 g0, g1;
            g0[0] = (_Float16)f0.x; g0[1] = (_Float16)f0.y; g0[2] = (_Float16)f0.z; g0[3] = (_Float16)f0.w;
            g0[4] = (_Float16)f1.x; g0[5] = (_Float16)f1.y; g0[6] = (_Float16)f1.z; g0[7] = (_Float16)f1.w;
            g1[0] = (_Float16)f2.x; g1[1] = (_Float16)f2.y; g1[2] = (_Float16)f2.z; g1[3] = (_Float16)f2.w;
            g1[4] = (_Float16)f3.x; g1[5] = (_Float16)f3.y; g1[6] = (_Float16)f3.z; g1[7] = (_Float16)f3.w;
            Bh[sg * 128 + srow]       = g0;
            Bh[(sg + 1) * 128 + srow] = g1;
        }
        __syncthreads();

        half8 vb[4];
#pragma unroll
        for (int c = 0; c < 4; c++) vb[c] = Bh[quad * 128 + wc + c * 16 + lid];
#pragma unroll
        for (int r = 0; r < 4; r++) {
            half8 va = Ah[quad * 128 + wr + r * 16 + lid];
#pragma unroll
            for (int c = 0; c < 4; c++)
                acc[r][c] = __builtin_amdgcn_mfma_f32_16x16x32_f16(va, vb[c], acc[r][c], 0, 0, 0);
        }
        __syncthreads();
    }

    float* Sb = S + (size_t)b * N * N;
#pragma unroll
    for (int r = 0; r < 4; r++) {
#pragma unroll
        for (int c = 0; c < 4; c++) {
#pragma unroll
            for (int e = 0; e < 4; e++) {
                const int grow = row0A + wr + r * 16 + quad * 4 + e;
                const int gcol = row0B + wc + c * 16 + lid;
                const float vv = acc[r][c][e];
                Sb[(size_t)grow * N + gcol] = vv;
                if (ti != tj) Sb[(size_t)gcol * N + grow] = vv;
            }
        }
    }
}

// ---------------------------------------------------------------------------
// Kernel 2: per row -- ballot-popcount bisection for a pivot P with
// #{S' > P+d} <= 31 and #{S' >= P-d} >= 32; band [P-d, P+d] rechecked with
// wave-cooperative exact fp32 dots; exact threshold among band; emit
// 512-bit adjacency mask + deg^-0.5. One wave per row, 4 rows/block.
// ---------------------------------------------------------------------------
__global__ __launch_bounds__(256) void thresh_mask(const float* __restrict__ S,
                                                   const float* __restrict__ x,
                                                   unsigned long long* __restrict__ masks,
                                                   float* __restrict__ dinv) {
    const int row  = blockIdx.x * 4 + (threadIdx.x >> 6);
    const int lane = threadIdx.x & 63;
    const float* Srow = S + (size_t)row * N;

    float v0[8];
#pragma unroll
    for (int k = 0; k < 8; k++) v0[k] = Srow[lane + 64 * k];   // col = lane + 64k

    // --- bisection: invariant cnt(lo) >= 32, cnt(hi) <= 31, cnt(p)=#{v>p} ---
    float lo = -1400.f, hi = 1400.f;   // |S'| <= ~1300 (diag chi2 max) + margin
    for (int it = 0; it < BISECT_ITERS; it++) {
        const float mid = 0.5f * (lo + hi);
        int c = 0;
#pragma unroll
        for (int k = 0; k < 8; k++) c += __popcll(__ballot(v0[k] > mid));
        if (c >= K_NEIGH) lo = mid; else hi = mid;
    }
    const float P   = 0.5f * (lo + hi);
    const float hiB = P + DELTA, loB = P - DELTA;

    // certainly-in count (<= 31 by construction)
    int cA = 0;
#pragma unroll
    for (int k = 0; k < 8; k++) cA += __popcll(__ballot(v0[k] > hiB));
    const int m_need = K_NEIGH - cA;   // >= 1

    // band candidates: one per lane
    int cnt = 0, myj = -1;
#pragma unroll
    for (int kq = 0; kq < 8; kq++) {
        unsigned long long bm = __ballot(v0[kq] >= loB && v0[kq] <= hiB);
        while (bm) {
            int bl = __ffsll(bm) - 1;
            bm &= bm - 1;
            if (cnt == lane) myj = bl + 64 * kq;
            cnt++;
        }
    }
    const int nc = cnt < 64 ? cnt : 64;

    // wave-cooperative exact dots: lane holds xi[q*256 + lane*4 .. +3]
    const int bb_ = row >> 9, ii = row & (N - 1);
    const float* xi = x + ((size_t)bb_ * N + ii) * C;
    float4 ai[4];
#pragma unroll
    for (int q = 0; q < 4; q++) ai[q] = *(const float4*)(xi + q * 256 + lane * 4);

    float ex = -INFINITY;
    for (int c2 = 0; c2 < nc; c2++) {
        const int j = __shfl(myj, c2);
        const float* xj = x + ((size_t)bb_ * N + j) * C;
        float s = 0.f;
#pragma unroll
        for (int q = 0; q < 4; q++) {
            float4 bv = *(const float4*)(xj + q * 256 + lane * 4);
            s = fmaf(ai[q].x, bv.x, s);
            s = fmaf(ai[q].y, bv.y, s);
            s = fmaf(ai[q].z, bv.z, s);
            s = fmaf(ai[q].w, bv.w, s);
        }
#pragma unroll
        for (int off = 32; off > 0; off >>= 1) s += __shfl_xor(s, off);
        if (lane == c2) ex = s;   // deterministic per (i,j)
    }

    // exact threshold T = m_need-th largest band value (tie-correct)
    float val = ex, T = -INFINITY;
    for (int it = 0; it < m_need; it++) {
        float M = val;
#pragma unroll
        for (int off = 32; off > 0; off >>= 1) M = fmaxf(M, __shfl_xor(M, off));
        T = M;
        unsigned long long ball = __ballot(val == M);
        int first = __ffsll(ball) - 1;
        if (lane == first) val = -INFINITY;
    }
    const int dec = (lane < nc && ex >= T) ? 1 : 0;

    // adjacency bits: certain-above -> 1, band -> exact decision, else 0
    int bits[8];
#pragma unroll
    for (int kq = 0; kq < 8; kq++) bits[kq] = (v0[kq] > hiB) ? 1 : 0;
    for (int c2 = 0; c2 < nc; c2++) {
        int j = __shfl(myj, c2);
        int d = __shfl(dec, c2);
        if ((j & 63) == lane) bits[j >> 6] = d;
    }

    unsigned long long msk[8];
    int deg = 0;
#pragma unroll
    for (int kq = 0; kq < 8; kq++) {
        msk[kq] = __ballot(bits[kq] != 0);
        deg += __popcll(msk[kq]);
    }
    if (lane == 0) {
#pragma unroll
        for (int kq = 0; kq < 8; kq++) masks[(size_t)row * 8 + kq] = msk[kq];
        dinv[row] = rsqrtf((float)deg);
    }
}

// ---------------------------------------------------------------------------
// Kernel 3: out[b,i,j] = maskbit ? dinv[b,i]*dinv[b,j] : 0  (writes over S')
// ---------------------------------------------------------------------------
__global__ __launch_bounds__(256) void scale_adj(float* __restrict__ Sout,
                                                 const unsigned long long* __restrict__ masks,
                                                 const float* __restrict__ dinv) {
    const int idx = blockIdx.x * 256 + threadIdx.x;   // float4 index
    const int jq = idx & 127;
    const int i  = (idx >> 7) & (N - 1);
    const int b  = idx >> 16;
    const int row = (b << 9) | i;
    const int j0 = jq * 4;

    const unsigned long long mk = masks[(size_t)row * 8 + (j0 >> 6)];
    const float di = dinv[row];
    float4 dj = ((const float4*)dinv)[(b << 7) | jq];

    float4 o;
    o.x = ((mk >> ((j0 + 0) & 63)) & 1ull) ? di * dj.x : 0.f;
    o.y = ((mk >> ((j0 + 1) & 63)) & 1ull) ? di * dj.y : 0.f;
    o.z = ((mk >> ((j0 + 2) & 63)) & 1ull) ? di * dj.z : 0.f;
    o.w = ((mk >> ((j0 + 3) & 63)) & 1ull) ? di * dj.w : 0.f;
    ((float4*)Sout)[idx] = o;
}

// ---------------------------------------------------------------------------
extern "C" void kernel_launch(void* const* d_in, const int* in_sizes, int n_in,
                              void* d_out, int out_size, void* d_ws, size_t ws_size,
                              hipStream_t stream) {
    const float* x = (const float*)d_in[0];
    float* out = (float*)d_out;                      // stages S', then final out
    unsigned long long* masks = (unsigned long long*)d_ws;     // B*N*8 u64 = 2MB
    float* dinv = (float*)(masks + (size_t)B * N * 8);         // B*N floats

    dim3 g1(B, 10);                                  // upper-tri pairs of 4 strips
    gemm_f16<<<g1, 256, 0, stream>>>(x, out);
    thresh_mask<<<B * N / 4, 256, 0, stream>>>(out, x, masks, dinv);
    const int total4 = B * N * N / 4;
    scale_adj<<<total4 / 256, 256, 0, stream>>>(out, masks, dinv);
}